// Round 2
// baseline (50679.697 us; speedup 1.0000x reference)
//
#include <hip/hip_runtime.h>
#include <stddef.h>

// CFRMClassifier R2: k-split GRU scan — 4 CUs cooperate per batch element.
// Each block streams 1/4 of w_hh (384KB/step), exchanges fp32 gate partials
// via LLC with agent-scope atomics + per-b 4-way flag sync.

typedef unsigned short u16;
typedef short s8v __attribute__((ext_vector_type(8)));
typedef float f4v __attribute__((ext_vector_type(4)));

#define B_ 64
#define T_ 1024
#define H_ 512
#define G_ 1536
#define C_ 32
#define NCLS_ 1000
#define KCLS_ 16448

#define AGENT __HIP_MEMORY_SCOPE_AGENT

__device__ __forceinline__ u16 f2bf(float f) {
    unsigned u = __float_as_uint(f);
    unsigned r = (u + 0x7fffu + ((u >> 16) & 1u)) >> 16;
    return (u16)r;
}
__device__ __forceinline__ float b2f(u16 x) { return __uint_as_float(((unsigned)x) << 16); }
__device__ __forceinline__ float bflo(unsigned u) { return __uint_as_float(u << 16); }
__device__ __forceinline__ float bfhi(unsigned u) { return __uint_as_float(u & 0xffff0000u); }
__device__ __forceinline__ float sigmoidf_(float x) { return 1.0f / (1.0f + __expf(-x)); }
__device__ __forceinline__ float tanhf_(float x) { return 1.0f - 2.0f / (1.0f + __expf(2.0f * x)); }

// ---------- prep kernels ----------
__global__ void k_cast_wih(const float* __restrict__ src, u16* __restrict__ dst) {
    int i = blockIdx.x * 256 + threadIdx.x;
    if (i < G_ * H_) dst[i] = f2bf(src[i]);
}

// wQ[(k4*1536 + j)*2 + u] = pack(w_hh[j][4k4+2u], w_hh[j][4k4+2u+1]), k4 in [0,128)
__global__ void k_pack_whh4(const float* __restrict__ w_hh, uint2* __restrict__ wQ) {
    int idx = blockIdx.x * 256 + threadIdx.x;
    if (idx >= 128 * G_) return;
    int k4 = idx / G_, j = idx % G_;
    const float* wr = w_hh + (size_t)j * H_ + 4 * k4;
    uint2 v;
    v.x = (unsigned)f2bf(wr[0]) | ((unsigned)f2bf(wr[1]) << 16);
    v.y = (unsigned)f2bf(wr[2]) | ((unsigned)f2bf(wr[3]) << 16);
    wQ[idx] = v;
}

__global__ void k_decay(float* __restrict__ decay) {
    int t = blockIdx.x * 256 + threadIdx.x;
    if (t < T_) decay[t] = powf(0.85f, (float)(T_ - 1 - t));
}

__global__ void k_zero_flags(unsigned* __restrict__ flags) {
    int i = blockIdx.x * 256 + threadIdx.x;
    if (i < 4096) flags[i] = 0u;
}

__global__ void k_zero_flatT(float* __restrict__ flatT) {
    int i = blockIdx.x * 256 + threadIdx.x;
    if (i < KCLS_ * B_) flatT[i] = 0.f;
}

// ---------- embedding gather + bf16 cast ----------
__global__ __launch_bounds__(256) void k_embed(const int* __restrict__ tokens,
                                               const float* __restrict__ emb,
                                               u16* __restrict__ X) {
    int g = blockIdx.x * 256 + threadIdx.x;
    int m = g >> 6, c8 = g & 63;
    int tok = tokens[m];
    const float4* src = (const float4*)(emb + (size_t)tok * H_ + c8 * 8);
    float4 f0 = src[0], f1 = src[1];
    uint4 pk;
    pk.x = (unsigned)f2bf(f0.x) | ((unsigned)f2bf(f0.y) << 16);
    pk.y = (unsigned)f2bf(f0.z) | ((unsigned)f2bf(f0.w) << 16);
    pk.z = (unsigned)f2bf(f1.x) | ((unsigned)f2bf(f1.y) << 16);
    pk.w = (unsigned)f2bf(f1.z) | ((unsigned)f2bf(f1.w) << 16);
    *(uint4*)(X + (size_t)m * H_ + c8 * 8) = pk;
}

// ---------- xp GEMM (bf16 MFMA), unchanged from R1 ----------
__global__ __launch_bounds__(256) void k_xp(const u16* __restrict__ X,
                                            const u16* __restrict__ Wih,
                                            const float* __restrict__ b_ih,
                                            u16* __restrict__ xp) {
    __shared__ u16 Bs[128 * 48];
    int tid = threadIdx.x;
    int bid = blockIdx.x;
    int m0 = (bid / 12) * 64;
    int n0 = (bid % 12) * 128;
    int w = tid >> 6, lane = tid & 63;
    int lm = lane & 15, q = lane >> 4;
    f4v acc[8];
#pragma unroll
    for (int i = 0; i < 8; i++) acc[i] = (f4v){0.f, 0.f, 0.f, 0.f};
    int arow = m0 + w * 16 + lm;
    const u16* Aptr = X + (size_t)arow * H_ + q * 8;
    int srow = tid >> 1, shalf = tid & 1;
    for (int kk = 0; kk < H_; kk += 32) {
        const uint4* src = (const uint4*)(Wih + (size_t)(n0 + srow) * H_ + kk + shalf * 16);
        uint4 v0 = src[0], v1 = src[1];
        uint4* dst = (uint4*)(Bs + srow * 48 + shalf * 16);
        dst[0] = v0; dst[1] = v1;
        __syncthreads();
        s8v a = *(const s8v*)(Aptr + kk);
#pragma unroll
        for (int nt = 0; nt < 8; nt++) {
            s8v bf = *(const s8v*)(Bs + (nt * 16 + lm) * 48 + q * 8);
            acc[nt] = __builtin_amdgcn_mfma_f32_16x16x32_bf16(a, bf, acc[nt], 0, 0, 0);
        }
        __syncthreads();
    }
#pragma unroll
    for (int nt = 0; nt < 8; nt++) {
        int col = n0 + nt * 16 + lm;
        float bias = b_ih[col];
#pragma unroll
        for (int r = 0; r < 4; r++) {
            int row = m0 + w * 16 + q * 4 + r;
            xp[(size_t)row * G_ + col] = f2bf(acc[nt][r] + bias);
        }
    }
}

// ---------- k-split GRU scan ----------
// grid = 256 blocks; block x -> (b,s): s=(x>>3)&3, b=(x&7)+8*(x>>5)
// (same-b group lands on one XCD under round-robin %8 placement)
__global__ __launch_bounds__(512) void k_scan4(const uint2* __restrict__ wQ,
                                               const u16* __restrict__ xp,
                                               const float* __restrict__ b_hh,
                                               float* __restrict__ hseq,
                                               float* __restrict__ pbuf,
                                               unsigned* __restrict__ flags) {
    int x = blockIdx.x;
    int s = (x >> 3) & 3;
    int b = (x & 7) + ((x >> 5) << 3);
    int tid = threadIdx.x;
    __shared__ float hl[128];    // own h slice (fp32)
    __shared__ float pl[1536];   // own partials (avoid LLC round trip for own)
    if (tid < 128) hl[tid] = 0.f;
    float hprev = 0.f;
    float bhr = 0.f, bhz = 0.f, bhn = 0.f;
    int jo = s * 128 + (tid & 127);
    if (tid < 128) { bhr = b_hh[jo]; bhz = b_hh[H_ + jo]; bhn = b_hh[2 * H_ + jo]; }
    const u16* xpb = xp + (size_t)b * T_ * G_;
    unsigned* flg = flags + (size_t)b * 64;  // flag[b][s'] at flg[s'*16] (64B padded)
    const uint2* wbase = wQ + (size_t)(s * 32) * G_ + tid;  // rows tid, +512, +1024
    __syncthreads();
    for (int t = 0; t < T_; t++) {
        // prefetch xp for the update phase (independent of sync)
        float xr = 0.f, xz = 0.f, xn = 0.f;
        if (tid < 128) {
            const u16* xt = xpb + (size_t)t * G_;
            xr = b2f(xt[jo]); xz = b2f(xt[H_ + jo]); xn = b2f(xt[2 * H_ + jo]);
        }
        float a0 = 0.f, a1 = 0.f, a2 = 0.f;
#pragma unroll 4
        for (int kl = 0; kl < 32; kl++) {
            const uint2* wp = wbase + (size_t)kl * G_;
            uint2 w0 = wp[0];
            uint2 w1 = wp[512];
            uint2 w2 = wp[1024];
            float4 h4 = *(const float4*)(hl + 4 * kl);
            a0 = fmaf(bflo(w0.x), h4.x, a0); a0 = fmaf(bfhi(w0.x), h4.y, a0);
            a0 = fmaf(bflo(w0.y), h4.z, a0); a0 = fmaf(bfhi(w0.y), h4.w, a0);
            a1 = fmaf(bflo(w1.x), h4.x, a1); a1 = fmaf(bfhi(w1.x), h4.y, a1);
            a1 = fmaf(bflo(w1.y), h4.z, a1); a1 = fmaf(bfhi(w1.y), h4.w, a1);
            a2 = fmaf(bflo(w2.x), h4.x, a2); a2 = fmaf(bfhi(w2.x), h4.y, a2);
            a2 = fmaf(bflo(w2.y), h4.z, a2); a2 = fmaf(bfhi(w2.y), h4.w, a2);
        }
        pl[tid] = a0; pl[tid + 512] = a1; pl[tid + 1024] = a2;
        float* pw = pbuf + (((size_t)(t & 1) * B_ + b) * 4 + s) * G_;
        __hip_atomic_store(pw + tid,        a0, __ATOMIC_RELAXED, AGENT);
        __hip_atomic_store(pw + tid + 512,  a1, __ATOMIC_RELAXED, AGENT);
        __hip_atomic_store(pw + tid + 1024, a2, __ATOMIC_RELAXED, AGENT);
        __threadfence();
        __syncthreads();   // all stores drained (vmcnt0) + pl visible
        if (tid == 0)
            __hip_atomic_store(&flg[s * 16], (unsigned)(t + 1), __ATOMIC_RELEASE, AGENT);
        if (tid < 4 && tid != s) {
            while (__hip_atomic_load(&flg[tid * 16], __ATOMIC_ACQUIRE, AGENT) < (unsigned)(t + 1)) {}
        }
        __syncthreads();
        if (tid < 128) {
            float r0 = pl[jo], z0 = pl[512 + jo], n0 = pl[1024 + jo];
            const float* pr = pbuf + ((size_t)(t & 1) * B_ + b) * 4 * G_;
#pragma unroll
            for (int s2 = 0; s2 < 4; s2++) {
                if (s2 == s) continue;
                const float* q = pr + (size_t)s2 * G_;
                r0 += __hip_atomic_load(q + jo,        __ATOMIC_RELAXED, AGENT);
                z0 += __hip_atomic_load(q + 512 + jo,  __ATOMIC_RELAXED, AGENT);
                n0 += __hip_atomic_load(q + 1024 + jo, __ATOMIC_RELAXED, AGENT);
            }
            float r = sigmoidf_(xr + r0 + bhr);
            float z = sigmoidf_(xz + z0 + bhz);
            float n = tanhf_(xn + r * (n0 + bhn));
            float hn = (1.f - z) * n + z * hprev;
            hprev = hn;
            hl[tid] = hn;
            hseq[((size_t)t * B_ + b) * H_ + jo] = hn;
        }
        __syncthreads();
    }
}

// ---------- decay-weighted & plain sums of h_seq ----------
__global__ __launch_bounds__(512) void k_hw(const float* __restrict__ hseq,
                                            const float* __restrict__ decay,
                                            float* __restrict__ hwT,
                                            float* __restrict__ hsumT) {
    int b = blockIdx.x, h = threadIdx.x;
    float aw = 0.f, as = 0.f;
    for (int t = 0; t < T_; t++) {
        float v = hseq[((size_t)t * B_ + b) * H_ + h];
        aw = fmaf(decay[t], v, aw);
        as += v;
    }
    hwT[h * B_ + b] = aw;
    hsumT[h * B_ + b] = as;
}

// ---------- spreads, chunked over t (8 chunks) + atomicAdd ----------
__global__ __launch_bounds__(512) void k_sd8(const float* __restrict__ hseq,
                                             const float* __restrict__ ws,
                                             const float* __restrict__ bs,
                                             const float* __restrict__ decay,
                                             float* __restrict__ flatT) {
    int b = blockIdx.x & 63, chunk = blockIdx.x >> 6;
    int t0 = chunk * 128;
    int tid = threadIdx.x;
    __shared__ float hl[2][512];
    int c = tid >> 4, p = tid & 15;
    float wreg[32];
#pragma unroll
    for (int i = 0; i < 32; i++) wreg[i] = ws[c * H_ + p + 16 * i];
    float bsc = bs[c];
    float acc = 0.f;
    hl[0][tid] = hseq[((size_t)t0 * B_ + b) * H_ + tid];
    __syncthreads();
    for (int tt = 0; tt < 128; tt++) {
        float nxt = 0.f;
        if (tt < 127) nxt = hseq[((size_t)(t0 + tt + 1) * B_ + b) * H_ + tid];
        int pg = tt & 1;
        float partial = 0.f;
#pragma unroll
        for (int i = 0; i < 32; i++) partial = fmaf(wreg[i], hl[pg][p + 16 * i], partial);
        partial += __shfl_xor(partial, 1, 16);
        partial += __shfl_xor(partial, 2, 16);
        partial += __shfl_xor(partial, 4, 16);
        partial += __shfl_xor(partial, 8, 16);
        acc = fmaf(decay[t0 + tt], sigmoidf_(partial + bsc), acc);
        __syncthreads();
        hl[pg ^ 1][tid] = nxt;
        __syncthreads();
    }
    if (p == 0) atomicAdd(&flatT[(c * 514 + 512) * B_ + b], 0.15f * acc);
}

// ---------- weights -> softmax -> nw rows ----------
__global__ __launch_bounds__(1024) void k_weights(const float* __restrict__ hsumT,
                                                  const float* __restrict__ ww,
                                                  const float* __restrict__ bw,
                                                  float* __restrict__ flatT) {
    int tid = threadIdx.x;
    __shared__ float wmat[C_ * B_];
    __shared__ float mb[B_], sb[B_];
    int b = tid & 63;
    int c0 = tid >> 6;
    float a0 = 0.f, a1 = 0.f;
    for (int h = 0; h < H_; h++) {
        float hv = hsumT[h * B_ + b];
        a0 = fmaf(ww[c0 * H_ + h], hv, a0);
        a1 = fmaf(ww[(c0 + 16) * H_ + h], hv, a1);
    }
    wmat[c0 * B_ + b] = a0 + 1024.0f * bw[c0];
    wmat[(c0 + 16) * B_ + b] = a1 + 1024.0f * bw[c0 + 16];
    __syncthreads();
    if (tid < 64) {
        float m = -1e30f;
        for (int c = 0; c < C_; c++) m = fmaxf(m, wmat[c * B_ + tid]);
        float sum = 0.f;
        for (int c = 0; c < C_; c++) sum += __expf(wmat[c * B_ + tid] - m);
        mb[tid] = m;
        sb[tid] = 1.0f / sum;
    }
    __syncthreads();
    flatT[(c0 * 514 + 513) * B_ + b] = __expf(wmat[c0 * B_ + b] - mb[b]) * sb[b];
    flatT[((c0 + 16) * 514 + 513) * B_ + b] = __expf(wmat[(c0 + 16) * B_ + b] - mb[b]) * sb[b];
}

// ---------- centers rows ----------
__global__ __launch_bounds__(64) void k_centersT(const float* __restrict__ hwT,
                                                 const float* __restrict__ wc,
                                                 const float* __restrict__ bc,
                                                 float* __restrict__ flatT) {
    int b = threadIdx.x;
    int k0 = blockIdx.x * 8;
    float acc[8] = {0, 0, 0, 0, 0, 0, 0, 0};
    for (int h = 0; h < H_; h++) {
        float hv = hwT[h * B_ + b];
#pragma unroll
        for (int r = 0; r < 8; r++) acc[r] = fmaf(wc[(size_t)(k0 + r) * H_ + h], hv, acc[r]);
    }
#pragma unroll
    for (int r = 0; r < 8; r++) {
        int k = k0 + r;
        int c = k >> 9, i = k & 511;
        flatT[(c * 514 + i) * B_ + b] = 0.15f * (acc[r] + (1.0f / 0.15f) * bc[k]);
    }
}

// ---------- classifier ----------
__global__ __launch_bounds__(256) void k_cls(const float* __restrict__ flatT,
                                             const float* __restrict__ wcls,
                                             const float* __restrict__ bcls,
                                             float* __restrict__ out) {
    int tid = threadIdx.x;
    int wv = tid >> 6, b = tid & 63;
    int j0 = blockIdx.x * 8;
    __shared__ float red[4][8][64];
    float acc[8] = {0, 0, 0, 0, 0, 0, 0, 0};
    for (int i = 0; i < 4112; i++) {
        int k = wv * 4112 + i;
        float fv = flatT[k * B_ + b];
#pragma unroll
        for (int r = 0; r < 8; r++) acc[r] = fmaf(wcls[(size_t)(j0 + r) * KCLS_ + k], fv, acc[r]);
    }
#pragma unroll
    for (int r = 0; r < 8; r++) red[wv][r][b] = acc[r];
    __syncthreads();
    for (int rr = tid; rr < 512; rr += 256) {
        int r = rr >> 6, bb = rr & 63;
        float sum = red[0][r][bb] + red[1][r][bb] + red[2][r][bb] + red[3][r][bb];
        out[bb * NCLS_ + j0 + r] = sum + bcls[j0 + r];
    }
}

extern "C" void kernel_launch(void* const* d_in, const int* in_sizes, int n_in,
                              void* d_out, int out_size, void* d_ws, size_t ws_size,
                              hipStream_t stream) {
    const int*   tokens = (const int*)d_in[0];
    const float* emb    = (const float*)d_in[1];
    const float* w_ih   = (const float*)d_in[2];
    const float* w_hh   = (const float*)d_in[3];
    const float* b_ih   = (const float*)d_in[4];
    const float* b_hh   = (const float*)d_in[5];
    const float* wc     = (const float*)d_in[6];
    const float* bc     = (const float*)d_in[7];
    const float* ws     = (const float*)d_in[8];
    const float* bs     = (const float*)d_in[9];
    const float* ww     = (const float*)d_in[10];
    const float* bw     = (const float*)d_in[11];
    const float* wcls   = (const float*)d_in[12];
    const float* bcls   = (const float*)d_in[13];
    float* out = (float*)d_out;

    char* w = (char*)d_ws;
    u16*      xp    = (u16*)(w + 0);                     // 201,326,592
    float*    hseq  = (float*)(w + 201326592);           // 134,217,728
    u16*      X16   = (u16*)(w + 335544320);             //  67,108,864 (later aliased)
    u16*      Wih16 = (u16*)(w + 402653184);             //   1,572,864
    uint2*    wQ    = (uint2*)(w + 404226048);           //   1,572,864
    float*    decay = (float*)(w + 405798912);           //       4,096
    float*    hwT   = (float*)(w + 405803008);           //     131,072
    float*    hsumT = (float*)(w + 405934080);           //     131,072
    float*    flatT = (float*)(w + 406065152);           //   4,210,688
    // aliased into X16's region (X16 dead after k_xp):
    float*    pbuf  = (float*)(w + 335544320);           //   3,145,728 (2*64*4*1536*4)
    unsigned* flags = (unsigned*)(w + 335544320 + 3145728); // 16,384

    k_cast_wih<<<dim3((G_ * H_ + 255) / 256), dim3(256), 0, stream>>>(w_ih, Wih16);
    k_pack_whh4<<<dim3((128 * G_ + 255) / 256), dim3(256), 0, stream>>>(w_hh, wQ);
    k_decay<<<dim3(4), dim3(256), 0, stream>>>(decay);
    k_embed<<<dim3(16384), dim3(256), 0, stream>>>(tokens, emb, X16);
    k_xp<<<dim3(12288), dim3(256), 0, stream>>>(X16, Wih16, b_ih, xp);
    k_zero_flags<<<dim3(16), dim3(256), 0, stream>>>(flags);   // after k_xp: aliases X16
    k_zero_flatT<<<dim3((KCLS_ * B_ + 255) / 256), dim3(256), 0, stream>>>(flatT);
    k_scan4<<<dim3(256), dim3(512), 0, stream>>>(wQ, xp, b_hh, hseq, pbuf, flags);
    k_hw<<<dim3(64), dim3(512), 0, stream>>>(hseq, decay, hwT, hsumT);
    k_sd8<<<dim3(512), dim3(512), 0, stream>>>(hseq, ws, bs, decay, flatT);
    k_weights<<<dim3(1), dim3(1024), 0, stream>>>(hsumT, ww, bw, flatT);
    k_centersT<<<dim3(2048), dim3(64), 0, stream>>>(hwT, wc, bc, flatT);
    k_cls<<<dim3(125), dim3(256), 0, stream>>>(flatT, wcls, bcls, out);
}

// Round 3
// 17186.647 us; speedup vs baseline: 2.9488x; 2.9488x over previous
//
#include <hip/hip_runtime.h>
#include <stddef.h>

// CFRMClassifier R3: revert to monolithic per-b scan (R2's cross-CU sync cost
// ~30us/step due to agent-scope fence L2 writebacks). Scan now streams w_hh
// with dwordx4 (8 bf16/load) targeting the ~144 GB/s/CU L2-return ceiling.

typedef unsigned short u16;
typedef short s8v __attribute__((ext_vector_type(8)));
typedef float f4v __attribute__((ext_vector_type(4)));

#define B_ 64
#define T_ 1024
#define H_ 512
#define G_ 1536
#define C_ 32
#define NCLS_ 1000
#define KCLS_ 16448

__device__ __forceinline__ u16 f2bf(float f) {
    unsigned u = __float_as_uint(f);
    unsigned r = (u + 0x7fffu + ((u >> 16) & 1u)) >> 16;
    return (u16)r;
}
__device__ __forceinline__ float b2f(u16 x) { return __uint_as_float(((unsigned)x) << 16); }
__device__ __forceinline__ float bflo(unsigned u) { return __uint_as_float(u << 16); }
__device__ __forceinline__ float bfhi(unsigned u) { return __uint_as_float(u & 0xffff0000u); }
__device__ __forceinline__ float sigmoidf_(float x) { return 1.0f / (1.0f + __expf(-x)); }
__device__ __forceinline__ float tanhf_(float x) { return 1.0f - 2.0f / (1.0f + __expf(2.0f * x)); }

// ---------- prep kernels ----------
__global__ void k_cast_wih(const float* __restrict__ src, u16* __restrict__ dst) {
    int i = blockIdx.x * 256 + threadIdx.x;
    if (i < G_ * H_) dst[i] = f2bf(src[i]);
}

// wV[k8*1536 + j] = uint4 packing w_hh[j][8*k8 .. 8*k8+7] as bf16 pairs
__global__ void k_pack_whh8(const float* __restrict__ w_hh, uint4* __restrict__ wV) {
    int idx = blockIdx.x * 256 + threadIdx.x;
    if (idx >= 64 * G_) return;
    int k8 = idx / G_, j = idx % G_;
    const float* wr = w_hh + (size_t)j * H_ + 8 * k8;
    uint4 v;
    v.x = (unsigned)f2bf(wr[0]) | ((unsigned)f2bf(wr[1]) << 16);
    v.y = (unsigned)f2bf(wr[2]) | ((unsigned)f2bf(wr[3]) << 16);
    v.z = (unsigned)f2bf(wr[4]) | ((unsigned)f2bf(wr[5]) << 16);
    v.w = (unsigned)f2bf(wr[6]) | ((unsigned)f2bf(wr[7]) << 16);
    wV[idx] = v;
}

__global__ void k_decay(float* __restrict__ decay) {
    int t = blockIdx.x * 256 + threadIdx.x;
    if (t < T_) decay[t] = powf(0.85f, (float)(T_ - 1 - t));
}

// zero hwT+hsumT+flatT (contiguous region, 1,118,208 floats)
__global__ void k_zero(float* __restrict__ p, int n) {
    int i = blockIdx.x * 256 + threadIdx.x;
    if (i < n) p[i] = 0.f;
}

// ---------- embedding gather + bf16 cast ----------
__global__ __launch_bounds__(256) void k_embed(const int* __restrict__ tokens,
                                               const float* __restrict__ emb,
                                               u16* __restrict__ X) {
    int g = blockIdx.x * 256 + threadIdx.x;
    int m = g >> 6, c8 = g & 63;
    int tok = tokens[m];
    const float4* src = (const float4*)(emb + (size_t)tok * H_ + c8 * 8);
    float4 f0 = src[0], f1 = src[1];
    uint4 pk;
    pk.x = (unsigned)f2bf(f0.x) | ((unsigned)f2bf(f0.y) << 16);
    pk.y = (unsigned)f2bf(f0.z) | ((unsigned)f2bf(f0.w) << 16);
    pk.z = (unsigned)f2bf(f1.x) | ((unsigned)f2bf(f1.y) << 16);
    pk.w = (unsigned)f2bf(f1.z) | ((unsigned)f2bf(f1.w) << 16);
    *(uint4*)(X + (size_t)m * H_ + c8 * 8) = pk;
}

// ---------- xp GEMM (bf16 MFMA) ----------
__global__ __launch_bounds__(256) void k_xp(const u16* __restrict__ X,
                                            const u16* __restrict__ Wih,
                                            const float* __restrict__ b_ih,
                                            u16* __restrict__ xp) {
    __shared__ u16 Bs[128 * 48];
    int tid = threadIdx.x;
    int bid = blockIdx.x;
    int m0 = (bid / 12) * 64;
    int n0 = (bid % 12) * 128;
    int w = tid >> 6, lane = tid & 63;
    int lm = lane & 15, q = lane >> 4;
    f4v acc[8];
#pragma unroll
    for (int i = 0; i < 8; i++) acc[i] = (f4v){0.f, 0.f, 0.f, 0.f};
    int arow = m0 + w * 16 + lm;
    const u16* Aptr = X + (size_t)arow * H_ + q * 8;
    int srow = tid >> 1, shalf = tid & 1;
    for (int kk = 0; kk < H_; kk += 32) {
        const uint4* src = (const uint4*)(Wih + (size_t)(n0 + srow) * H_ + kk + shalf * 16);
        uint4 v0 = src[0], v1 = src[1];
        uint4* dst = (uint4*)(Bs + srow * 48 + shalf * 16);
        dst[0] = v0; dst[1] = v1;
        __syncthreads();
        s8v a = *(const s8v*)(Aptr + kk);
#pragma unroll
        for (int nt = 0; nt < 8; nt++) {
            s8v bf = *(const s8v*)(Bs + (nt * 16 + lm) * 48 + q * 8);
            acc[nt] = __builtin_amdgcn_mfma_f32_16x16x32_bf16(a, bf, acc[nt], 0, 0, 0);
        }
        __syncthreads();
    }
#pragma unroll
    for (int nt = 0; nt < 8; nt++) {
        int col = n0 + nt * 16 + lm;
        float bias = b_ih[col];
#pragma unroll
        for (int r = 0; r < 4; r++) {
            int row = m0 + w * 16 + q * 4 + r;
            xp[(size_t)row * G_ + col] = f2bf(acc[nt][r] + bias);
        }
    }
}

// ---------- GRU scan: 64 blocks (one per b) x 512 threads ----------
// per step each thread streams 3 gate rows as 64x3 dwordx4 loads (1.57MB/CU/step)
__global__ __launch_bounds__(512) void k_scan(const uint4* __restrict__ wV,
                                              const u16* __restrict__ xp,
                                              const float* __restrict__ b_hh,
                                              float* __restrict__ hseq) {
    int b = blockIdx.x, j = threadIdx.x;
    __shared__ float hl[2][512];
    hl[0][j] = 0.f;
    hl[1][j] = 0.f;
    float hprev = 0.f;
    float bhr = b_hh[j], bhz = b_hh[H_ + j], bhn = b_hh[2 * H_ + j];
    const u16* xpb = xp + (size_t)b * T_ * G_;
    const uint4* w0 = wV + j;
    __syncthreads();
    for (int t = 0; t < T_; t++) {
        const u16* xt = xpb + (size_t)t * G_;
        float xr = b2f(xt[j]);
        float xz = b2f(xt[H_ + j]);
        float xn = b2f(xt[2 * H_ + j]);
        const float4* h4 = (const float4*)hl[t & 1];
        float ar = 0.f, az = 0.f, an = 0.f;
#pragma unroll 4
        for (int k8 = 0; k8 < 64; k8++) {
            uint4 wr = w0[(size_t)k8 * G_];
            uint4 wz = w0[(size_t)k8 * G_ + 512];
            uint4 wn = w0[(size_t)k8 * G_ + 1024];
            float4 ha = h4[2 * k8], hb = h4[2 * k8 + 1];
            ar = fmaf(bflo(wr.x), ha.x, ar); ar = fmaf(bfhi(wr.x), ha.y, ar);
            ar = fmaf(bflo(wr.y), ha.z, ar); ar = fmaf(bfhi(wr.y), ha.w, ar);
            ar = fmaf(bflo(wr.z), hb.x, ar); ar = fmaf(bfhi(wr.z), hb.y, ar);
            ar = fmaf(bflo(wr.w), hb.z, ar); ar = fmaf(bfhi(wr.w), hb.w, ar);
            az = fmaf(bflo(wz.x), ha.x, az); az = fmaf(bfhi(wz.x), ha.y, az);
            az = fmaf(bflo(wz.y), ha.z, az); az = fmaf(bfhi(wz.y), ha.w, az);
            az = fmaf(bflo(wz.z), hb.x, az); az = fmaf(bfhi(wz.z), hb.y, az);
            az = fmaf(bflo(wz.w), hb.z, az); az = fmaf(bfhi(wz.w), hb.w, az);
            an = fmaf(bflo(wn.x), ha.x, an); an = fmaf(bfhi(wn.x), ha.y, an);
            an = fmaf(bflo(wn.y), ha.z, an); an = fmaf(bfhi(wn.y), ha.w, an);
            an = fmaf(bflo(wn.z), hb.x, an); an = fmaf(bfhi(wn.z), hb.y, an);
            an = fmaf(bflo(wn.w), hb.z, an); an = fmaf(bfhi(wn.w), hb.w, an);
        }
        float r = sigmoidf_(xr + ar + bhr);
        float z = sigmoidf_(xz + az + bhz);
        float n = tanhf_(xn + r * (an + bhn));
        float hn = (1.f - z) * n + z * hprev;
        hl[(t + 1) & 1][j] = hn;   // write other buffer: no race with readers of hl[t&1]
        hprev = hn;
        hseq[((size_t)t * B_ + b) * H_ + j] = hn;
        __syncthreads();
    }
}

// ---------- decay-weighted & plain sums of h_seq, 8 t-chunks ----------
__global__ __launch_bounds__(512) void k_hw8(const float* __restrict__ hseq,
                                             const float* __restrict__ decay,
                                             float* __restrict__ hwT,
                                             float* __restrict__ hsumT) {
    int b = blockIdx.x & 63, chunk = blockIdx.x >> 6;
    int h = threadIdx.x;
    int t0 = chunk * 128;
    float aw = 0.f, as = 0.f;
    for (int tt = 0; tt < 128; tt++) {
        float v = hseq[((size_t)(t0 + tt) * B_ + b) * H_ + h];
        aw = fmaf(decay[t0 + tt], v, aw);
        as += v;
    }
    atomicAdd(&hwT[h * B_ + b], aw);
    atomicAdd(&hsumT[h * B_ + b], as);
}

// ---------- spreads, chunked over t (8 chunks) + atomicAdd ----------
__global__ __launch_bounds__(512) void k_sd8(const float* __restrict__ hseq,
                                             const float* __restrict__ ws,
                                             const float* __restrict__ bs,
                                             const float* __restrict__ decay,
                                             float* __restrict__ flatT) {
    int b = blockIdx.x & 63, chunk = blockIdx.x >> 6;
    int t0 = chunk * 128;
    int tid = threadIdx.x;
    __shared__ float hl[2][512];
    int c = tid >> 4, p = tid & 15;
    float wreg[32];
#pragma unroll
    for (int i = 0; i < 32; i++) wreg[i] = ws[c * H_ + p + 16 * i];
    float bsc = bs[c];
    float acc = 0.f;
    hl[0][tid] = hseq[((size_t)t0 * B_ + b) * H_ + tid];
    __syncthreads();
    for (int tt = 0; tt < 128; tt++) {
        float nxt = 0.f;
        if (tt < 127) nxt = hseq[((size_t)(t0 + tt + 1) * B_ + b) * H_ + tid];
        int pg = tt & 1;
        float partial = 0.f;
#pragma unroll
        for (int i = 0; i < 32; i++) partial = fmaf(wreg[i], hl[pg][p + 16 * i], partial);
        partial += __shfl_xor(partial, 1, 16);
        partial += __shfl_xor(partial, 2, 16);
        partial += __shfl_xor(partial, 4, 16);
        partial += __shfl_xor(partial, 8, 16);
        acc = fmaf(decay[t0 + tt], sigmoidf_(partial + bsc), acc);
        __syncthreads();
        hl[pg ^ 1][tid] = nxt;
        __syncthreads();
    }
    if (p == 0) atomicAdd(&flatT[(c * 514 + 512) * B_ + b], 0.15f * acc);
}

// ---------- weights -> softmax -> nw rows ----------
__global__ __launch_bounds__(1024) void k_weights(const float* __restrict__ hsumT,
                                                  const float* __restrict__ ww,
                                                  const float* __restrict__ bw,
                                                  float* __restrict__ flatT) {
    int tid = threadIdx.x;
    __shared__ float wmat[C_ * B_];
    __shared__ float mb[B_], sb[B_];
    int b = tid & 63;
    int c0 = tid >> 6;
    float a0 = 0.f, a1 = 0.f;
    for (int h = 0; h < H_; h++) {
        float hv = hsumT[h * B_ + b];
        a0 = fmaf(ww[c0 * H_ + h], hv, a0);
        a1 = fmaf(ww[(c0 + 16) * H_ + h], hv, a1);
    }
    wmat[c0 * B_ + b] = a0 + 1024.0f * bw[c0];
    wmat[(c0 + 16) * B_ + b] = a1 + 1024.0f * bw[c0 + 16];
    __syncthreads();
    if (tid < 64) {
        float m = -1e30f;
        for (int c = 0; c < C_; c++) m = fmaxf(m, wmat[c * B_ + tid]);
        float sum = 0.f;
        for (int c = 0; c < C_; c++) sum += __expf(wmat[c * B_ + tid] - m);
        mb[tid] = m;
        sb[tid] = 1.0f / sum;
    }
    __syncthreads();
    flatT[(c0 * 514 + 513) * B_ + b] = __expf(wmat[c0 * B_ + b] - mb[b]) * sb[b];
    flatT[((c0 + 16) * 514 + 513) * B_ + b] = __expf(wmat[(c0 + 16) * B_ + b] - mb[b]) * sb[b];
}

// ---------- centers rows ----------
__global__ __launch_bounds__(64) void k_centersT(const float* __restrict__ hwT,
                                                 const float* __restrict__ wc,
                                                 const float* __restrict__ bc,
                                                 float* __restrict__ flatT) {
    int b = threadIdx.x;
    int k0 = blockIdx.x * 8;
    float acc[8] = {0, 0, 0, 0, 0, 0, 0, 0};
    for (int h = 0; h < H_; h++) {
        float hv = hwT[h * B_ + b];
#pragma unroll
        for (int r = 0; r < 8; r++) acc[r] = fmaf(wc[(size_t)(k0 + r) * H_ + h], hv, acc[r]);
    }
#pragma unroll
    for (int r = 0; r < 8; r++) {
        int k = k0 + r;
        int c = k >> 9, i = k & 511;
        flatT[(c * 514 + i) * B_ + b] = 0.15f * (acc[r] + (1.0f / 0.15f) * bc[k]);
    }
}

// ---------- classifier ----------
__global__ __launch_bounds__(256) void k_cls(const float* __restrict__ flatT,
                                             const float* __restrict__ wcls,
                                             const float* __restrict__ bcls,
                                             float* __restrict__ out) {
    int tid = threadIdx.x;
    int wv = tid >> 6, b = tid & 63;
    int j0 = blockIdx.x * 8;
    __shared__ float red[4][8][64];
    float acc[8] = {0, 0, 0, 0, 0, 0, 0, 0};
    for (int i = 0; i < 4112; i++) {
        int k = wv * 4112 + i;
        float fv = flatT[k * B_ + b];
#pragma unroll
        for (int r = 0; r < 8; r++) acc[r] = fmaf(wcls[(size_t)(j0 + r) * KCLS_ + k], fv, acc[r]);
    }
#pragma unroll
    for (int r = 0; r < 8; r++) red[wv][r][b] = acc[r];
    __syncthreads();
    for (int rr = tid; rr < 512; rr += 256) {
        int r = rr >> 6, bb = rr & 63;
        float sum = red[0][r][bb] + red[1][r][bb] + red[2][r][bb] + red[3][r][bb];
        out[bb * NCLS_ + j0 + r] = sum + bcls[j0 + r];
    }
}

extern "C" void kernel_launch(void* const* d_in, const int* in_sizes, int n_in,
                              void* d_out, int out_size, void* d_ws, size_t ws_size,
                              hipStream_t stream) {
    const int*   tokens = (const int*)d_in[0];
    const float* emb    = (const float*)d_in[1];
    const float* w_ih   = (const float*)d_in[2];
    const float* w_hh   = (const float*)d_in[3];
    const float* b_ih   = (const float*)d_in[4];
    const float* b_hh   = (const float*)d_in[5];
    const float* wc     = (const float*)d_in[6];
    const float* bc     = (const float*)d_in[7];
    const float* ws     = (const float*)d_in[8];
    const float* bs     = (const float*)d_in[9];
    const float* ww     = (const float*)d_in[10];
    const float* bw     = (const float*)d_in[11];
    const float* wcls   = (const float*)d_in[12];
    const float* bcls   = (const float*)d_in[13];
    float* out = (float*)d_out;

    char* w = (char*)d_ws;
    u16*   xp    = (u16*)(w + 0);                  // 201,326,592
    float* hseq  = (float*)(w + 201326592);        // 134,217,728
    u16*   X16   = (u16*)(w + 335544320);          //  67,108,864
    u16*   Wih16 = (u16*)(w + 402653184);          //   1,572,864
    uint4* wV    = (uint4*)(w + 404226048);        //   1,572,864
    float* decay = (float*)(w + 405798912);        //       4,096
    float* hwT   = (float*)(w + 405803008);        //     131,072
    float* hsumT = (float*)(w + 405934080);        //     131,072
    float* flatT = (float*)(w + 406065152);        //   4,210,688
    // zero region: hwT..flatT contiguous = 4,472,832 B = 1,118,208 floats

    k_cast_wih<<<dim3((G_ * H_ + 255) / 256), dim3(256), 0, stream>>>(w_ih, Wih16);
    k_pack_whh8<<<dim3((64 * G_ + 255) / 256), dim3(256), 0, stream>>>(w_hh, wV);
    k_decay<<<dim3(4), dim3(256), 0, stream>>>(decay);
    k_zero<<<dim3((1118208 + 255) / 256), dim3(256), 0, stream>>>(hwT, 1118208);
    k_embed<<<dim3(16384), dim3(256), 0, stream>>>(tokens, emb, X16);
    k_xp<<<dim3(12288), dim3(256), 0, stream>>>(X16, Wih16, b_ih, xp);
    k_scan<<<dim3(64), dim3(512), 0, stream>>>(wV, xp, b_hh, hseq);
    k_hw8<<<dim3(512), dim3(512), 0, stream>>>(hseq, decay, hwT, hsumT);
    k_sd8<<<dim3(512), dim3(512), 0, stream>>>(hseq, ws, bs, decay, flatT);
    k_weights<<<dim3(1), dim3(1024), 0, stream>>>(hsumT, ww, bw, flatT);
    k_centersT<<<dim3(2048), dim3(64), 0, stream>>>(hwT, wc, bc, flatT);
    k_cls<<<dim3(125), dim3(256), 0, stream>>>(flatT, wcls, bcls, out);
}

// Round 4
// 11486.101 us; speedup vs baseline: 4.4123x; 1.4963x over previous
//
#include <hip/hip_runtime.h>
#include <stddef.h>

// CFRMClassifier R4: N-split GRU scan — 4 blocks per batch element, each owns a
// 128-wide h slice and streams only its 384 gate rows (384KB/step). h exchanged
// through LLC with RELAXED agent atomics ONLY (no fences -> no wbl2/inv, the R2
// killer). Flags give per-step backpressure; __syncthreads provides vmcnt(0).

typedef unsigned short u16;
typedef short s8v __attribute__((ext_vector_type(8)));
typedef float f4v __attribute__((ext_vector_type(4)));

#define B_ 64
#define T_ 1024
#define H_ 512
#define G_ 1536
#define C_ 32
#define NCLS_ 1000
#define KCLS_ 16448

#define AGENT __HIP_MEMORY_SCOPE_AGENT

__device__ __forceinline__ u16 f2bf(float f) {
    unsigned u = __float_as_uint(f);
    unsigned r = (u + 0x7fffu + ((u >> 16) & 1u)) >> 16;
    return (u16)r;
}
__device__ __forceinline__ float b2f(u16 x) { return __uint_as_float(((unsigned)x) << 16); }
__device__ __forceinline__ float bflo(unsigned u) { return __uint_as_float(u << 16); }
__device__ __forceinline__ float bfhi(unsigned u) { return __uint_as_float(u & 0xffff0000u); }
__device__ __forceinline__ float sigmoidf_(float x) { return 1.0f / (1.0f + __expf(-x)); }
__device__ __forceinline__ float tanhf_(float x) { return 1.0f - 2.0f / (1.0f + __expf(2.0f * x)); }

// ---------- prep kernels ----------
__global__ void k_cast_wih(const float* __restrict__ src, u16* __restrict__ dst) {
    int i = blockIdx.x * 256 + threadIdx.x;
    if (i < G_ * H_) dst[i] = f2bf(src[i]);
}

// wN[((s*64 + k8)*384 + g)] = uint4 of w_hh[j][8k8..8k8+7], j = (g>>7)*512 + s*128 + (g&127)
__global__ void k_pack_whhN(const float* __restrict__ w_hh, uint4* __restrict__ wN) {
    int idx = blockIdx.x * 256 + threadIdx.x;      // 4*64*384 = 98304
    if (idx >= 4 * 64 * 384) return;
    int g = idx % 384;
    int k8 = (idx / 384) % 64;
    int s = idx / (384 * 64);
    int j = (g >> 7) * 512 + s * 128 + (g & 127);
    const float* wr = w_hh + (size_t)j * H_ + 8 * k8;
    uint4 v;
    v.x = (unsigned)f2bf(wr[0]) | ((unsigned)f2bf(wr[1]) << 16);
    v.y = (unsigned)f2bf(wr[2]) | ((unsigned)f2bf(wr[3]) << 16);
    v.z = (unsigned)f2bf(wr[4]) | ((unsigned)f2bf(wr[5]) << 16);
    v.w = (unsigned)f2bf(wr[6]) | ((unsigned)f2bf(wr[7]) << 16);
    wN[idx] = v;
}

__global__ void k_decay(float* __restrict__ decay) {
    int t = blockIdx.x * 256 + threadIdx.x;
    if (t < T_) decay[t] = powf(0.85f, (float)(T_ - 1 - t));
}

__global__ void k_zero(float* __restrict__ p, int n) {
    int i = blockIdx.x * 256 + threadIdx.x;
    if (i < n) p[i] = 0.f;
}

// ---------- embedding gather + bf16 cast ----------
__global__ __launch_bounds__(256) void k_embed(const int* __restrict__ tokens,
                                               const float* __restrict__ emb,
                                               u16* __restrict__ X) {
    int g = blockIdx.x * 256 + threadIdx.x;
    int m = g >> 6, c8 = g & 63;
    int tok = tokens[m];
    const float4* src = (const float4*)(emb + (size_t)tok * H_ + c8 * 8);
    float4 f0 = src[0], f1 = src[1];
    uint4 pk;
    pk.x = (unsigned)f2bf(f0.x) | ((unsigned)f2bf(f0.y) << 16);
    pk.y = (unsigned)f2bf(f0.z) | ((unsigned)f2bf(f0.w) << 16);
    pk.z = (unsigned)f2bf(f1.x) | ((unsigned)f2bf(f1.y) << 16);
    pk.w = (unsigned)f2bf(f1.z) | ((unsigned)f2bf(f1.w) << 16);
    *(uint4*)(X + (size_t)m * H_ + c8 * 8) = pk;
}

// ---------- xp GEMM (bf16 MFMA) ----------
__global__ __launch_bounds__(256) void k_xp(const u16* __restrict__ X,
                                            const u16* __restrict__ Wih,
                                            const float* __restrict__ b_ih,
                                            u16* __restrict__ xp) {
    __shared__ u16 Bs[128 * 48];
    int tid = threadIdx.x;
    int bid = blockIdx.x;
    int m0 = (bid / 12) * 64;
    int n0 = (bid % 12) * 128;
    int w = tid >> 6, lane = tid & 63;
    int lm = lane & 15, q = lane >> 4;
    f4v acc[8];
#pragma unroll
    for (int i = 0; i < 8; i++) acc[i] = (f4v){0.f, 0.f, 0.f, 0.f};
    int arow = m0 + w * 16 + lm;
    const u16* Aptr = X + (size_t)arow * H_ + q * 8;
    int srow = tid >> 1, shalf = tid & 1;
    for (int kk = 0; kk < H_; kk += 32) {
        const uint4* src = (const uint4*)(Wih + (size_t)(n0 + srow) * H_ + kk + shalf * 16);
        uint4 v0 = src[0], v1 = src[1];
        uint4* dst = (uint4*)(Bs + srow * 48 + shalf * 16);
        dst[0] = v0; dst[1] = v1;
        __syncthreads();
        s8v a = *(const s8v*)(Aptr + kk);
#pragma unroll
        for (int nt = 0; nt < 8; nt++) {
            s8v bf = *(const s8v*)(Bs + (nt * 16 + lm) * 48 + q * 8);
            acc[nt] = __builtin_amdgcn_mfma_f32_16x16x32_bf16(a, bf, acc[nt], 0, 0, 0);
        }
        __syncthreads();
    }
#pragma unroll
    for (int nt = 0; nt < 8; nt++) {
        int col = n0 + nt * 16 + lm;
        float bias = b_ih[col];
#pragma unroll
        for (int r = 0; r < 4; r++) {
            int row = m0 + w * 16 + q * 4 + r;
            xp[(size_t)row * G_ + col] = f2bf(acc[nt][r] + bias);
        }
    }
}

// ---------- N-split GRU scan ----------
// grid 256: s = x&3 (one weight slice per XCD), b = x>>2.
// threads 0..383: row g (gate=g>>7, out=g&127), full-k dot in 2 phases.
// threads 384..511: poll peer flags + pull peer h slices from LLC.
__global__ __launch_bounds__(512, 2) void k_scan4(const uint4* __restrict__ wN,
                                                  const u16* __restrict__ xp,
                                                  const float* __restrict__ b_hh,
                                                  float* __restrict__ hseq,
                                                  float* __restrict__ hx,
                                                  unsigned* __restrict__ flags) {
    int x = blockIdx.x;
    int s = x & 3, b = x >> 2;
    int tid = threadIdx.x;
    __shared__ float hl[2][512];
    __shared__ float dotb[3][128];
    hl[0][tid] = 0.f;
    const uint4* wS = wN + (size_t)s * (64 * 384);
    int io = tid & 127;
    int jo = s * 128 + io;
    float bh = 0.f;
    if (tid < 384) bh = b_hh[(tid >> 7) * H_ + jo];
    float hprev = 0.f;
    const u16* xpb = xp + (size_t)b * T_ * G_;
    unsigned* flg = flags + b * 64;
    __syncthreads();
    for (int t = 0; t < T_; t++) {
        int par = t & 1;
        float xr = 0.f, xz = 0.f, xn = 0.f;
        if (tid < 128) {
            const u16* xt = xpb + (size_t)t * G_;
            xr = b2f(xt[jo]); xz = b2f(xt[512 + jo]); xn = b2f(xt[1024 + jo]);
        }
        float acc = 0.f;
        if (tid < 384) {
            // phase A: own k-quarter (h slice we computed ourselves)
            const float4* h4 = (const float4*)&hl[par][s * 128];
            const uint4* wp = wS + (size_t)(16 * s) * 384 + tid;
#pragma unroll
            for (int kk = 0; kk < 16; kk++) {
                uint4 wv = wp[(size_t)kk * 384];
                float4 ha = h4[2 * kk], hb = h4[2 * kk + 1];
                acc = fmaf(bflo(wv.x), ha.x, acc); acc = fmaf(bfhi(wv.x), ha.y, acc);
                acc = fmaf(bflo(wv.y), ha.z, acc); acc = fmaf(bfhi(wv.y), ha.w, acc);
                acc = fmaf(bflo(wv.z), hb.x, acc); acc = fmaf(bfhi(wv.z), hb.y, acc);
                acc = fmaf(bflo(wv.w), hb.z, acc); acc = fmaf(bfhi(wv.w), hb.w, acc);
            }
        } else if (t > 0) {
            int p = tid - 384;  // 0..127
            const float* hr = hx + ((size_t)par * B_ + b) * 512;
#pragma unroll
            for (int d = 1; d < 4; d++) {
                int s2 = (s + d) & 3;
                const unsigned* fl = flg + s2 * 16;
                while (__hip_atomic_load(fl, __ATOMIC_RELAXED, AGENT) < (unsigned)t)
                    __builtin_amdgcn_s_sleep(1);
                __asm__ __volatile__("" ::: "memory");
                hl[par][s2 * 128 + p] =
                    __hip_atomic_load(hr + s2 * 128 + p, __ATOMIC_RELAXED, AGENT);
            }
        }
        __syncthreads();
        if (tid < 384) {
            // phase B: remaining 3 k-quarters
#pragma unroll
            for (int d = 1; d < 4; d++) {
                int s2 = (s + d) & 3;
                const float4* h4 = (const float4*)&hl[par][s2 * 128];
                const uint4* wp = wS + (size_t)(16 * s2) * 384 + tid;
#pragma unroll
                for (int kk = 0; kk < 16; kk++) {
                    uint4 wv = wp[(size_t)kk * 384];
                    float4 ha = h4[2 * kk], hb = h4[2 * kk + 1];
                    acc = fmaf(bflo(wv.x), ha.x, acc); acc = fmaf(bfhi(wv.x), ha.y, acc);
                    acc = fmaf(bflo(wv.y), ha.z, acc); acc = fmaf(bfhi(wv.y), ha.w, acc);
                    acc = fmaf(bflo(wv.z), hb.x, acc); acc = fmaf(bfhi(wv.z), hb.y, acc);
                    acc = fmaf(bflo(wv.w), hb.z, acc); acc = fmaf(bfhi(wv.w), hb.w, acc);
                }
            }
            dotb[tid >> 7][io] = acc + bh;
        }
        __syncthreads();
        if (tid < 128) {
            float r = sigmoidf_(xr + dotb[0][io]);
            float z = sigmoidf_(xz + dotb[1][io]);
            float n = tanhf_(xn + r * dotb[2][io]);
            float hn = (1.f - z) * n + z * hprev;
            hprev = hn;
            hl[par ^ 1][jo] = hn;
            __hip_atomic_store(hx + ((size_t)(par ^ 1) * B_ + b) * 512 + jo, hn,
                               __ATOMIC_RELAXED, AGENT);
            hseq[((size_t)t * B_ + b) * H_ + jo] = hn;
        }
        __syncthreads();  // implies vmcnt(0): publishes complete at LLC
        if (tid == 0)
            __hip_atomic_store(flg + s * 16, (unsigned)(t + 1), __ATOMIC_RELAXED, AGENT);
    }
}

// ---------- decay-weighted & plain sums of h_seq, 8 t-chunks ----------
__global__ __launch_bounds__(512) void k_hw8(const float* __restrict__ hseq,
                                             const float* __restrict__ decay,
                                             float* __restrict__ hwT,
                                             float* __restrict__ hsumT) {
    int b = blockIdx.x & 63, chunk = blockIdx.x >> 6;
    int h = threadIdx.x;
    int t0 = chunk * 128;
    float aw = 0.f, as = 0.f;
    for (int tt = 0; tt < 128; tt++) {
        float v = hseq[((size_t)(t0 + tt) * B_ + b) * H_ + h];
        aw = fmaf(decay[t0 + tt], v, aw);
        as += v;
    }
    atomicAdd(&hwT[h * B_ + b], aw);
    atomicAdd(&hsumT[h * B_ + b], as);
}

// ---------- spreads, chunked over t (8 chunks) + atomicAdd ----------
__global__ __launch_bounds__(512) void k_sd8(const float* __restrict__ hseq,
                                             const float* __restrict__ ws,
                                             const float* __restrict__ bs,
                                             const float* __restrict__ decay,
                                             float* __restrict__ flatT) {
    int b = blockIdx.x & 63, chunk = blockIdx.x >> 6;
    int t0 = chunk * 128;
    int tid = threadIdx.x;
    __shared__ float hl[2][512];
    int c = tid >> 4, p = tid & 15;
    float wreg[32];
#pragma unroll
    for (int i = 0; i < 32; i++) wreg[i] = ws[c * H_ + p + 16 * i];
    float bsc = bs[c];
    float acc = 0.f;
    hl[0][tid] = hseq[((size_t)t0 * B_ + b) * H_ + tid];
    __syncthreads();
    for (int tt = 0; tt < 128; tt++) {
        float nxt = 0.f;
        if (tt < 127) nxt = hseq[((size_t)(t0 + tt + 1) * B_ + b) * H_ + tid];
        int pg = tt & 1;
        float partial = 0.f;
#pragma unroll
        for (int i = 0; i < 32; i++) partial = fmaf(wreg[i], hl[pg][p + 16 * i], partial);
        partial += __shfl_xor(partial, 1, 16);
        partial += __shfl_xor(partial, 2, 16);
        partial += __shfl_xor(partial, 4, 16);
        partial += __shfl_xor(partial, 8, 16);
        acc = fmaf(decay[t0 + tt], sigmoidf_(partial + bsc), acc);
        __syncthreads();
        hl[pg ^ 1][tid] = nxt;
        __syncthreads();
    }
    if (p == 0) atomicAdd(&flatT[(c * 514 + 512) * B_ + b], 0.15f * acc);
}

// ---------- weights -> softmax -> nw rows ----------
__global__ __launch_bounds__(1024) void k_weights(const float* __restrict__ hsumT,
                                                  const float* __restrict__ ww,
                                                  const float* __restrict__ bw,
                                                  float* __restrict__ flatT) {
    int tid = threadIdx.x;
    __shared__ float wmat[C_ * B_];
    __shared__ float mb[B_], sb[B_];
    int b = tid & 63;
    int c0 = tid >> 6;
    float a0 = 0.f, a1 = 0.f;
    for (int h = 0; h < H_; h++) {
        float hv = hsumT[h * B_ + b];
        a0 = fmaf(ww[c0 * H_ + h], hv, a0);
        a1 = fmaf(ww[(c0 + 16) * H_ + h], hv, a1);
    }
    wmat[c0 * B_ + b] = a0 + 1024.0f * bw[c0];
    wmat[(c0 + 16) * B_ + b] = a1 + 1024.0f * bw[c0 + 16];
    __syncthreads();
    if (tid < 64) {
        float m = -1e30f;
        for (int c = 0; c < C_; c++) m = fmaxf(m, wmat[c * B_ + tid]);
        float sum = 0.f;
        for (int c = 0; c < C_; c++) sum += __expf(wmat[c * B_ + tid] - m);
        mb[tid] = m;
        sb[tid] = 1.0f / sum;
    }
    __syncthreads();
    flatT[(c0 * 514 + 513) * B_ + b] = __expf(wmat[c0 * B_ + b] - mb[b]) * sb[b];
    flatT[((c0 + 16) * 514 + 513) * B_ + b] = __expf(wmat[(c0 + 16) * B_ + b] - mb[b]) * sb[b];
}

// ---------- centers rows ----------
__global__ __launch_bounds__(64) void k_centersT(const float* __restrict__ hwT,
                                                 const float* __restrict__ wc,
                                                 const float* __restrict__ bc,
                                                 float* __restrict__ flatT) {
    int b = threadIdx.x;
    int k0 = blockIdx.x * 8;
    float acc[8] = {0, 0, 0, 0, 0, 0, 0, 0};
    for (int h = 0; h < H_; h++) {
        float hv = hwT[h * B_ + b];
#pragma unroll
        for (int r = 0; r < 8; r++) acc[r] = fmaf(wc[(size_t)(k0 + r) * H_ + h], hv, acc[r]);
    }
#pragma unroll
    for (int r = 0; r < 8; r++) {
        int k = k0 + r;
        int c = k >> 9, i = k & 511;
        flatT[(c * 514 + i) * B_ + b] = 0.15f * (acc[r] + (1.0f / 0.15f) * bc[k]);
    }
}

// ---------- classifier ----------
__global__ __launch_bounds__(256) void k_cls(const float* __restrict__ flatT,
                                             const float* __restrict__ wcls,
                                             const float* __restrict__ bcls,
                                             float* __restrict__ out) {
    int tid = threadIdx.x;
    int wv = tid >> 6, b = tid & 63;
    int j0 = blockIdx.x * 8;
    __shared__ float red[4][8][64];
    float acc[8] = {0, 0, 0, 0, 0, 0, 0, 0};
    for (int i = 0; i < 4112; i++) {
        int k = wv * 4112 + i;
        float fv = flatT[k * B_ + b];
#pragma unroll
        for (int r = 0; r < 8; r++) acc[r] = fmaf(wcls[(size_t)(j0 + r) * KCLS_ + k], fv, acc[r]);
    }
#pragma unroll
    for (int r = 0; r < 8; r++) red[wv][r][b] = acc[r];
    __syncthreads();
    for (int rr = tid; rr < 512; rr += 256) {
        int r = rr >> 6, bb = rr & 63;
        float sum = red[0][r][bb] + red[1][r][bb] + red[2][r][bb] + red[3][r][bb];
        out[bb * NCLS_ + j0 + r] = sum + bcls[j0 + r];
    }
}

extern "C" void kernel_launch(void* const* d_in, const int* in_sizes, int n_in,
                              void* d_out, int out_size, void* d_ws, size_t ws_size,
                              hipStream_t stream) {
    const int*   tokens = (const int*)d_in[0];
    const float* emb    = (const float*)d_in[1];
    const float* w_ih   = (const float*)d_in[2];
    const float* w_hh   = (const float*)d_in[3];
    const float* b_ih   = (const float*)d_in[4];
    const float* b_hh   = (const float*)d_in[5];
    const float* wc     = (const float*)d_in[6];
    const float* bc     = (const float*)d_in[7];
    const float* ws     = (const float*)d_in[8];
    const float* bs     = (const float*)d_in[9];
    const float* ww     = (const float*)d_in[10];
    const float* bw     = (const float*)d_in[11];
    const float* wcls   = (const float*)d_in[12];
    const float* bcls   = (const float*)d_in[13];
    float* out = (float*)d_out;

    char* w = (char*)d_ws;
    u16*      xp    = (u16*)(w + 0);                 // 201,326,592
    float*    hseq  = (float*)(w + 201326592);       // 134,217,728
    u16*      X16   = (u16*)(w + 335544320);         //  67,108,864 (dead after k_xp)
    u16*      Wih16 = (u16*)(w + 402653184);         //   1,572,864
    uint4*    wN    = (uint4*)(w + 404226048);       //   1,572,864
    float*    decay = (float*)(w + 405798912);       //       4,096
    float*    hwT   = (float*)(w + 405803008);       //     131,072
    float*    hsumT = (float*)(w + 405934080);       //     131,072
    float*    flatT = (float*)(w + 406065152);       //   4,210,688  (total 410,275,840)
    // aliased into X16's region after k_xp:
    float*    hx    = (float*)(w + 335544320);                 // 2*64*512*4 = 262,144
    unsigned* flags = (unsigned*)(w + 335544320 + 262144);     // 64*64*4    =  16,384

    k_cast_wih<<<dim3((G_ * H_ + 255) / 256), dim3(256), 0, stream>>>(w_ih, Wih16);
    k_pack_whhN<<<dim3((4 * 64 * 384 + 255) / 256), dim3(256), 0, stream>>>(w_hh, wN);
    k_decay<<<dim3(4), dim3(256), 0, stream>>>(decay);
    k_zero<<<dim3((1118208 + 255) / 256), dim3(256), 0, stream>>>(hwT, 1118208);
    k_embed<<<dim3(16384), dim3(256), 0, stream>>>(tokens, emb, X16);
    k_xp<<<dim3(12288), dim3(256), 0, stream>>>(X16, Wih16, b_ih, xp);
    k_zero<<<dim3(16), dim3(256), 0, stream>>>((float*)flags, 4096);  // after k_xp (aliases X16)
    k_scan4<<<dim3(256), dim3(512), 0, stream>>>(wN, xp, b_hh, hseq, hx, flags);
    k_hw8<<<dim3(512), dim3(512), 0, stream>>>(hseq, decay, hwT, hsumT);
    k_sd8<<<dim3(512), dim3(512), 0, stream>>>(hseq, ws, bs, decay, flatT);
    k_weights<<<dim3(1), dim3(1024), 0, stream>>>(hsumT, ww, bw, flatT);
    k_centersT<<<dim3(2048), dim3(64), 0, stream>>>(hwT, wc, bc, flatT);
    k_cls<<<dim3(125), dim3(256), 0, stream>>>(flatT, wcls, bcls, out);
}